// Round 1
// baseline (25256.718 us; speedup 1.0000x reference)
//
#include <hip/hip_runtime.h>
#include <hip/hip_bf16.h>
#include <math.h>

#define B_ 256
#define D_ 768
#define N_ 256
#define L_ 2
#define H_ 8
#define T_ 20
#define HD_ 96
#define D4_ 3072

typedef __hip_bfloat16 bf16;

__device__ __forceinline__ float gelu_f(float v) {
    return 0.5f * v * (1.0f + erff(v * 0.7071067811865476f));
}

__device__ __forceinline__ float blockSum(float v, float* red, int tid) {
    for (int off = 32; off; off >>= 1) v += __shfl_down(v, off, 64);
    int w = tid >> 6, lane = tid & 63;
    if (lane == 0) red[w] = v;
    __syncthreads();
    float r = red[0] + red[1] + red[2] + red[3];
    __syncthreads();
    return r;
}

// ---------------- init cp ----------------
__global__ void initcp_kernel(const float* __restrict__ past, float* __restrict__ cp) {
    int i = blockIdx.x * 256 + threadIdx.x;
    if (i < 2 * B_) cp[i] = past[(i >> 1) * 96 + 90 + (i & 1)];
}

// ---------------- context = concat(onehot, past, pad) @ w_qinit + b ----------------
__global__ __launch_bounds__(256) void context_kernel(const float* __restrict__ past,
                                                      const float* __restrict__ w_qinit,
                                                      const float* __restrict__ b_qinit,
                                                      const int* __restrict__ intent,
                                                      float* __restrict__ x) {
    int b = blockIdx.x, tid = threadIdx.x;
    __shared__ float ps[96];
    __shared__ int oidx;
    if (tid < 96) ps[tid] = past[b * 96 + tid];
    if (tid == 0) {
        int iv = intent[b] - 1;
        oidx = iv < 0 ? 0 : (iv > 2 ? 2 : iv);
    }
    __syncthreads();
    #pragma unroll
    for (int r = 0; r < 3; ++r) {
        int d = tid + r * 256;
        float acc = w_qinit[oidx * D_ + d] + b_qinit[d];
        #pragma unroll 8
        for (int p = 0; p < 96; ++p) acc += ps[p] * w_qinit[(3 + p) * D_ + d];
        x[b * D_ + d] = acc;
    }
}

// ---------------- K/V projection GEMM (tokens = feats^T + pos_enc) ----------------
__global__ __launch_bounds__(256) void kv_gemm(const float* __restrict__ feats,
                                               const float* __restrict__ pos_enc,
                                               const float* __restrict__ Wk,
                                               const float* __restrict__ bk,
                                               const float* __restrict__ Wv,
                                               const float* __restrict__ bv,
                                               bf16* __restrict__ Kt,
                                               bf16* __restrict__ Vv) {
    int ms = blockIdx.z;           // 0:K0 1:V0 2:K1 3:V1
    int l = ms >> 1, isV = ms & 1;
    const float* Wp = (isV ? Wv : Wk) + (size_t)l * D_ * D_;
    const float* bp = (isV ? bv : bk) + l * D_;
    int row0 = blockIdx.y * 64;
    int b = row0 >> 8;
    int n0 = row0 & 255;
    int e0 = blockIdx.x * 64;
    __shared__ __align__(16) float As[16][68];
    __shared__ __align__(16) float Bs[16][68];
    int tid = threadIdx.x;
    int am = tid & 63, ak = tid >> 6;
    int ty = tid >> 4, tx = tid & 15;
    float acc[4][4] = {};
    const size_t fbase = (size_t)b * D_ * N_;
    for (int k0 = 0; k0 < D_; k0 += 16) {
        #pragma unroll
        for (int r = 0; r < 4; ++r) {
            int k = ak + r * 4;
            As[k][am] = feats[fbase + (size_t)(k0 + k) * N_ + n0 + am]
                      + pos_enc[(size_t)(n0 + am) * D_ + k0 + k];
        }
        #pragma unroll
        for (int r = 0; r < 4; ++r) {
            int k = ak + r * 4;
            Bs[k][am] = Wp[(size_t)(k0 + k) * D_ + e0 + am];
        }
        __syncthreads();
        #pragma unroll
        for (int k = 0; k < 16; ++k) {
            float4 a4 = *(const float4*)&As[k][ty * 4];
            float4 b4 = *(const float4*)&Bs[k][tx * 4];
            float av[4] = {a4.x, a4.y, a4.z, a4.w};
            float bw[4] = {b4.x, b4.y, b4.z, b4.w};
            #pragma unroll
            for (int i = 0; i < 4; ++i)
                #pragma unroll
                for (int j = 0; j < 4; ++j) acc[i][j] += av[i] * bw[j];
        }
        __syncthreads();
    }
    #pragma unroll
    for (int i = 0; i < 4; ++i) {
        int n = n0 + ty * 4 + i;
        #pragma unroll
        for (int j = 0; j < 4; ++j) {
            int e = e0 + tx * 4 + j;
            float v = acc[i][j] + bp[e];
            int h = e / 96, hd = e % 96;
            size_t base = (size_t)(l * B_ + b) * H_ + h;
            if (isV) Vv[(base * N_ + n) * HD_ + hd] = __float2bfloat16(v);
            else     Kt[(base * HD_ + hd) * N_ + n] = __float2bfloat16(v);
        }
    }
}

// ---------------- generic small GEMM: C[256 x Nc] = act(A@W + bias) [+=] ----------------
template<int ACT, int ACCUM>
__global__ __launch_bounds__(256) void gemm64(const float* __restrict__ A,
                                              const float* __restrict__ W,
                                              const float* __restrict__ bias,
                                              float* __restrict__ C,
                                              int K, int Nc) {
    __shared__ __align__(16) float As[16][68];
    __shared__ __align__(16) float Bs[16][68];
    int tid = threadIdx.x;
    int m0 = blockIdx.y * 64;
    int e0 = blockIdx.x * 64;
    int lm = tid >> 4, lk = tid & 15;
    int be = tid & 63, bkk = tid >> 6;
    int ty = tid >> 4, tx = tid & 15;
    float acc[4][4] = {};
    for (int k0 = 0; k0 < K; k0 += 16) {
        #pragma unroll
        for (int r = 0; r < 4; ++r) {
            int m = lm + r * 16;
            As[lk][m] = A[(size_t)(m0 + m) * K + k0 + lk];
        }
        #pragma unroll
        for (int r = 0; r < 4; ++r) {
            int k = bkk + r * 4;
            Bs[k][be] = W[(size_t)(k0 + k) * Nc + e0 + be];
        }
        __syncthreads();
        #pragma unroll
        for (int k = 0; k < 16; ++k) {
            float4 a4 = *(const float4*)&As[k][ty * 4];
            float4 b4 = *(const float4*)&Bs[k][tx * 4];
            float av[4] = {a4.x, a4.y, a4.z, a4.w};
            float bw[4] = {b4.x, b4.y, b4.z, b4.w};
            #pragma unroll
            for (int i = 0; i < 4; ++i)
                #pragma unroll
                for (int j = 0; j < 4; ++j) acc[i][j] += av[i] * bw[j];
        }
        __syncthreads();
    }
    #pragma unroll
    for (int i = 0; i < 4; ++i) {
        int m = m0 + ty * 4 + i;
        #pragma unroll
        for (int j = 0; j < 4; ++j) {
            int e = e0 + tx * 4 + j;
            float v = acc[i][j] + bias[e];
            if (ACT == 1) v = gelu_f(v);
            size_t idx = (size_t)m * Nc + e;
            if (ACCUM) C[idx] += v;
            else       C[idx] = v;
        }
    }
}

// ---------------- LayerNorm ----------------
__global__ __launch_bounds__(256) void ln_kernel(const float* __restrict__ x,
                                                 float* __restrict__ y,
                                                 const float* __restrict__ g,
                                                 const float* __restrict__ bta) {
    int b = blockIdx.x, tid = threadIdx.x;
    float t[3];
    float s = 0, ss = 0;
    #pragma unroll
    for (int r = 0; r < 3; ++r) {
        int d = tid + r * 256;
        t[r] = x[b * D_ + d];
        s += t[r];
        ss += t[r] * t[r];
    }
    __shared__ float red[4];
    s = blockSum(s, red, tid);
    ss = blockSum(ss, red, tid);
    float mean = s * (1.0f / D_);
    float var = ss * (1.0f / D_) - mean * mean;
    float rinv = rsqrtf(var + 1e-5f);
    #pragma unroll
    for (int r = 0; r < 3; ++r) {
        int d = tid + r * 256;
        y[b * D_ + d] = (t[r] - mean) * rinv * g[d] + bta[d];
    }
}

// ---------------- pre-step: x += relu(LN(cp@w_pp+b_pp)) + te ----------------
__global__ __launch_bounds__(256) void prestep_kernel(float* __restrict__ x,
                                                      const float* __restrict__ cp,
                                                      const float* __restrict__ w_pp,
                                                      const float* __restrict__ b_pp,
                                                      const float* __restrict__ g_pp,
                                                      const float* __restrict__ be_pp,
                                                      const float* __restrict__ te) {
    int b = blockIdx.x, tid = threadIdx.x;
    float c0 = cp[b * 2], c1 = cp[b * 2 + 1];
    float t[3];
    float s = 0, ss = 0;
    #pragma unroll
    for (int r = 0; r < 3; ++r) {
        int d = tid + r * 256;
        t[r] = c0 * w_pp[d] + c1 * w_pp[D_ + d] + b_pp[d];
        s += t[r];
        ss += t[r] * t[r];
    }
    __shared__ float red[4];
    s = blockSum(s, red, tid);
    ss = blockSum(ss, red, tid);
    float mean = s * (1.0f / D_);
    float var = ss * (1.0f / D_) - mean * mean;
    float rinv = rsqrtf(var + 1e-5f);
    #pragma unroll
    for (int r = 0; r < 3; ++r) {
        int d = tid + r * 256;
        float pq = (t[r] - mean) * rinv * g_pp[d] + be_pp[d];
        pq = fmaxf(pq, 0.0f);
        x[b * D_ + d] += pq + te[d];
    }
}

// ---------------- single-query attention for one layer ----------------
__global__ __launch_bounds__(256) void attn_kernel(const float* __restrict__ q,
                                                   const bf16* __restrict__ Kt,
                                                   const bf16* __restrict__ Vv,
                                                   float* __restrict__ att) {
    int b = blockIdx.y, h = blockIdx.x, tid = threadIdx.x;
    __shared__ float qs[96];
    __shared__ float sc[256];
    __shared__ float red[4];
    __shared__ float opart[4][96];
    if (tid < 96) qs[tid] = q[b * D_ + h * 96 + tid];
    __syncthreads();
    const bf16* Kp = Kt + ((size_t)(b * H_ + h)) * HD_ * N_;
    float acc = 0;
    #pragma unroll 8
    for (int hd = 0; hd < 96; ++hd)
        acc += qs[hd] * __bfloat162float(Kp[hd * N_ + tid]);
    acc *= 0.10206207261596575f;   // 1/sqrt(96)
    int w = tid >> 6, lane = tid & 63;
    float m = acc;
    for (int off = 32; off; off >>= 1) m = fmaxf(m, __shfl_xor(m, off, 64));
    if (lane == 0) red[w] = m;
    __syncthreads();
    m = fmaxf(fmaxf(red[0], red[1]), fmaxf(red[2], red[3]));
    __syncthreads();
    float e = expf(acc - m);
    float ssum = e;
    for (int off = 32; off; off >>= 1) ssum += __shfl_xor(ssum, off, 64);
    if (lane == 0) red[w] = ssum;
    __syncthreads();
    float tot = red[0] + red[1] + red[2] + red[3];
    sc[tid] = e / tot;
    __syncthreads();
    // phase 2: o = a @ V
    const bf16* Vp = Vv + ((size_t)(b * H_ + h)) * N_ * HD_;
    float o0 = 0, o1 = 0;
    for (int i = 0; i < 64; ++i) {
        int n = w * 64 + i;
        float a = sc[n];
        const bf16* vrow = Vp + n * HD_;
        o0 += a * __bfloat162float(vrow[lane]);
        if (lane < 32) o1 += a * __bfloat162float(vrow[64 + lane]);
    }
    opart[w][lane] = o0;
    if (lane < 32) opart[w][64 + lane] = o1;
    __syncthreads();
    if (tid < 96) att[b * D_ + h * 96 + tid] =
        opart[0][tid] + opart[1][tid] + opart[2][tid] + opart[3][tid];
}

// ---------------- final: delta = dech @ w_dec2 + b_dec2; cp += delta; write out ----------------
__global__ __launch_bounds__(256) void final_kernel(const float* __restrict__ dech,
                                                    const float* __restrict__ w_dec2,
                                                    const float* __restrict__ b_dec2,
                                                    float* __restrict__ cp,
                                                    float* __restrict__ out,
                                                    int t) {
    int b = blockIdx.x, tid = threadIdx.x;
    float p0 = 0, p1 = 0;
    for (int k = tid; k < D_; k += 256) {
        float v = dech[b * D_ + k];
        p0 += v * w_dec2[k * 2];
        p1 += v * w_dec2[k * 2 + 1];
    }
    __shared__ float red[4];
    p0 = blockSum(p0, red, tid);
    p1 = blockSum(p1, red, tid);
    if (tid == 0) {
        float c0 = cp[b * 2] + p0 + b_dec2[0];
        float c1 = cp[b * 2 + 1] + p1 + b_dec2[1];
        cp[b * 2] = c0;
        cp[b * 2 + 1] = c1;
        out[(b * T_ + t) * 2] = c0;
        out[(b * T_ + t) * 2 + 1] = c1;
    }
}

extern "C" void kernel_launch(void* const* d_in, const int* in_sizes, int n_in,
                              void* d_out, int out_size, void* d_ws, size_t ws_size,
                              hipStream_t stream) {
    const float* feats   = (const float*)d_in[0];
    const float* past    = (const float*)d_in[1];
    const float* w_qinit = (const float*)d_in[2];
    const float* b_qinit = (const float*)d_in[3];
    const float* pos_enc = (const float*)d_in[4];
    const float* w_pp    = (const float*)d_in[5];
    const float* b_pp    = (const float*)d_in[6];
    const float* g_pp    = (const float*)d_in[7];
    const float* be_pp   = (const float*)d_in[8];
    const float* time_emb= (const float*)d_in[9];
    const float* Wq      = (const float*)d_in[10];
    const float* bq      = (const float*)d_in[11];
    const float* Wk      = (const float*)d_in[12];
    const float* bk      = (const float*)d_in[13];
    const float* Wv      = (const float*)d_in[14];
    const float* bv      = (const float*)d_in[15];
    const float* Wo      = (const float*)d_in[16];
    const float* bo      = (const float*)d_in[17];
    const float* ln1_g   = (const float*)d_in[18];
    const float* ln1_b   = (const float*)d_in[19];
    const float* W1      = (const float*)d_in[20];
    const float* b1      = (const float*)d_in[21];
    const float* W2      = (const float*)d_in[22];
    const float* b2      = (const float*)d_in[23];
    const float* ln2_g   = (const float*)d_in[24];
    const float* ln2_b   = (const float*)d_in[25];
    const float* w_dec1  = (const float*)d_in[26];
    const float* b_dec1  = (const float*)d_in[27];
    const float* w_dec2  = (const float*)d_in[28];
    const float* b_dec2  = (const float*)d_in[29];
    const int*   intent  = (const int*)d_in[30];
    float* out = (float*)d_out;

    // workspace carve-up
    char* wp = (char*)d_ws;
    const size_t kv_elems = (size_t)L_ * B_ * H_ * HD_ * N_;   // 100,663,296
    bf16* Kt = (bf16*)wp;           wp += kv_elems * sizeof(bf16);
    bf16* Vv = (bf16*)wp;           wp += kv_elems * sizeof(bf16);
    float* x   = (float*)wp;        wp += (size_t)B_ * D_ * 4;
    float* xn  = (float*)wp;        wp += (size_t)B_ * D_ * 4;
    float* q   = (float*)wp;        wp += (size_t)B_ * D_ * 4;
    float* att = (float*)wp;        wp += (size_t)B_ * D_ * 4;
    float* h1  = (float*)wp;        wp += (size_t)B_ * D4_ * 4;
    float* dech= (float*)wp;        wp += (size_t)B_ * D_ * 4;
    float* cp  = (float*)wp;        wp += (size_t)B_ * 2 * 4;

    // init
    initcp_kernel<<<2, 256, 0, stream>>>(past, cp);
    context_kernel<<<B_, 256, 0, stream>>>(past, w_qinit, b_qinit, intent, x);
    kv_gemm<<<dim3(12, 1024, 4), 256, 0, stream>>>(feats, pos_enc, Wk, bk, Wv, bv, Kt, Vv);

    for (int t = 0; t < T_; ++t) {
        prestep_kernel<<<B_, 256, 0, stream>>>(x, cp, w_pp, b_pp, g_pp, be_pp,
                                               time_emb + (size_t)t * D_);
        for (int l = 0; l < L_; ++l) {
            ln_kernel<<<B_, 256, 0, stream>>>(x, xn, ln1_g + l * D_, ln1_b + l * D_);
            gemm64<0, 0><<<dim3(12, 4), 256, 0, stream>>>(xn, Wq + (size_t)l * D_ * D_,
                                                          bq + l * D_, q, D_, D_);
            attn_kernel<<<dim3(H_, B_), 256, 0, stream>>>(q,
                Kt + (size_t)l * B_ * H_ * HD_ * N_,
                Vv + (size_t)l * B_ * H_ * N_ * HD_, att);
            gemm64<0, 1><<<dim3(12, 4), 256, 0, stream>>>(att, Wo + (size_t)l * D_ * D_,
                                                          bo + l * D_, x, D_, D_);
            ln_kernel<<<B_, 256, 0, stream>>>(x, xn, ln2_g + l * D_, ln2_b + l * D_);
            gemm64<1, 0><<<dim3(48, 4), 256, 0, stream>>>(xn, W1 + (size_t)l * D_ * D4_,
                                                          b1 + l * D4_, h1, D_, D4_);
            gemm64<0, 1><<<dim3(12, 4), 256, 0, stream>>>(h1, W2 + (size_t)l * D4_ * D_,
                                                          b2 + l * D_, x, D4_, D_);
        }
        gemm64<1, 0><<<dim3(12, 4), 256, 0, stream>>>(x, w_dec1, b_dec1, dech, D_, D_);
        final_kernel<<<B_, 256, 0, stream>>>(dech, w_dec2, b_dec2, cp, out, t);
    }
}

// Round 2
// 11105.585 us; speedup vs baseline: 2.2742x; 2.2742x over previous
//
#include <hip/hip_runtime.h>
#include <hip/hip_bf16.h>
#include <math.h>

#define B_ 256
#define D_ 768
#define N_ 256
#define L_ 2
#define H_ 8
#define T_ 20
#define HD_ 96
#define D4_ 3072

typedef float f32x4v __attribute__((ext_vector_type(4)));
typedef __bf16 bf16x8v __attribute__((ext_vector_type(8)));

union V16 { uint4 u; bf16x8v v; };

__device__ __forceinline__ ushort f2b(float f) {
    union { float f; unsigned u; } x{f};
    unsigned r = x.u + 0x7fffu + ((x.u >> 16) & 1u);
    return (ushort)(r >> 16);
}
__device__ __forceinline__ float b2f(ushort s) {
    union { unsigned u; float f; } x{(unsigned)s << 16};
    return x.f;
}
__device__ __forceinline__ float gelu_f(float v) {
    return 0.5f * v * (1.0f + erff(v * 0.7071067811865476f));
}
__device__ __forceinline__ float blockSum(float v, float* red, int tid) {
    for (int off = 32; off; off >>= 1) v += __shfl_down(v, off, 64);
    int w = tid >> 6, lane = tid & 63;
    if (lane == 0) red[w] = v;
    __syncthreads();
    float r = red[0] + red[1] + red[2] + red[3];
    __syncthreads();
    return r;
}

// ---------------- init cp ----------------
__global__ void initcp_kernel(const float* __restrict__ past, float* __restrict__ cp) {
    int i = blockIdx.x * 256 + threadIdx.x;
    if (i < 2 * B_) cp[i] = past[(i >> 1) * 96 + 90 + (i & 1)];
}

// ---------------- context ----------------
__global__ __launch_bounds__(256) void context_kernel(const float* __restrict__ past,
                                                      const float* __restrict__ w_qinit,
                                                      const float* __restrict__ b_qinit,
                                                      const int* __restrict__ intent,
                                                      float* __restrict__ x) {
    int b = blockIdx.x, tid = threadIdx.x;
    __shared__ float ps[96];
    __shared__ int oidx;
    if (tid < 96) ps[tid] = past[b * 96 + tid];
    if (tid == 0) {
        int iv = intent[b] - 1;
        oidx = iv < 0 ? 0 : (iv > 2 ? 2 : iv);
    }
    __syncthreads();
    #pragma unroll
    for (int r = 0; r < 3; ++r) {
        int d = tid + r * 256;
        float acc = w_qinit[oidx * D_ + d] + b_qinit[d];
        #pragma unroll 8
        for (int p = 0; p < 96; ++p) acc += ps[p] * w_qinit[(3 + p) * D_ + d];
        x[b * D_ + d] = acc;
    }
}

// ---------------- tokens bf16 k-major: tokens[(b*256+n)][d] = feats[b][d][n] + pos[n][d] ----------------
__global__ __launch_bounds__(256) void token_prep(const float* __restrict__ feats,
                                                  const float* __restrict__ pos_enc,
                                                  ushort* __restrict__ tokens) {
    int b = blockIdx.z;
    int d0 = blockIdx.x * 64, n0 = blockIdx.y * 64;
    __shared__ float tile[64][65];
    int tid = threadIdx.x;
    int nl = tid & 63, dl0 = tid >> 6;
    const float* fb = feats + ((size_t)b * D_ + d0) * N_ + n0;
    #pragma unroll
    for (int i = 0; i < 16; ++i) {
        int dl = dl0 + i * 4;
        tile[dl][nl] = fb[(size_t)dl * N_ + nl];
    }
    __syncthreads();
    int dq = (tid & 15) * 4;
    int ng = tid >> 4;
    #pragma unroll
    for (int i = 0; i < 4; ++i) {
        int nl2 = ng + i * 16;
        int n = n0 + nl2;
        float4 p = *(const float4*)(pos_enc + (size_t)n * D_ + d0 + dq);
        ushort4 o;
        o.x = f2b(tile[dq + 0][nl2] + p.x);
        o.y = f2b(tile[dq + 1][nl2] + p.y);
        o.z = f2b(tile[dq + 2][nl2] + p.z);
        o.w = f2b(tile[dq + 3][nl2] + p.w);
        *(ushort4*)&tokens[((size_t)b * N_ + n) * D_ + d0 + dq] = o;
    }
}

// ---------------- weight transpose (+ optional row scale) fp32[K][N] -> bf16[N][K] ----------------
__global__ __launch_bounds__(256) void transpose_w(const float* __restrict__ W,
                                                   ushort* __restrict__ out,
                                                   const float* __restrict__ scale,
                                                   int K, int N) {
    __shared__ float t[32][33];
    int k0 = blockIdx.y * 32, n0 = blockIdx.x * 32;
    int tx = threadIdx.x & 31, ty = threadIdx.x >> 5;
    #pragma unroll
    for (int i = 0; i < 4; ++i)
        t[ty + i * 8][tx] = W[(size_t)(k0 + ty + i * 8) * N + n0 + tx];
    __syncthreads();
    #pragma unroll
    for (int i = 0; i < 4; ++i) {
        int n = n0 + ty + i * 8, k = k0 + tx;
        float v = t[tx][ty + i * 8];
        if (scale) v *= scale[k];
        out[(size_t)n * K + k] = f2b(v);
    }
}

// ---------------- bias_eff = bias + b_ln @ W ----------------
__global__ __launch_bounds__(256) void bias_eff_kernel(const float* __restrict__ W,
                                                       const float* __restrict__ bias,
                                                       const float* __restrict__ lb,
                                                       float* __restrict__ be, int Nc) {
    int n = blockIdx.x * 256 + threadIdx.x;
    float a = bias[n];
    for (int k = 0; k < D_; ++k) a += lb[k] * W[(size_t)k * Nc + n];
    be[n] = a;
}

__global__ void kvbias_prep(const float* __restrict__ bk, const float* __restrict__ bv,
                            float* __restrict__ bc) {
    int i = blockIdx.x * 256 + threadIdx.x;
    int mi = i / D_, c = i % D_;
    int l = mi >> 1;
    bc[i] = (mi & 1 ? bv : bk)[l * D_ + c];
}

// ---------------- K/V projection: tokens[65536x768] @ Wkvt^T (3072 cols) ----------------
__global__ __launch_bounds__(256) void kv_gemm_mfma(const ushort* __restrict__ tokens,
                                                    const ushort* __restrict__ Wkvt,
                                                    const float* __restrict__ bias_kv,
                                                    ushort* __restrict__ Kt,
                                                    ushort* __restrict__ Vv) {
    int e0 = blockIdx.x * 128;            // 0..3071
    int mi = e0 / D_;                      // 0:K0 1:V0 2:K1 3:V1
    int ein = e0 % D_;
    int l = mi >> 1, isV = mi & 1;
    int m0 = blockIdx.y * 128;
    int b = m0 >> 8, ntok0 = m0 & 255;
    __shared__ ushort smem[17408];
    ushort* As = smem;
    ushort* Bs = smem + 128 * 40;
    int tid = threadIdx.x;
    int w = tid >> 6, lane = tid & 63, quad = lane >> 4, l16 = lane & 15;
    int wr = w >> 1, wc = w & 1;
    f32x4v acc[4][4];
    #pragma unroll
    for (int i = 0; i < 4; ++i)
        #pragma unroll
        for (int j = 0; j < 4; ++j) acc[i][j] = (f32x4v)(0.0f);

    for (int k0 = 0; k0 < D_; k0 += 32) {
        #pragma unroll
        for (int vv = 0; vv < 2; ++vv) {
            int v = tid + vv * 256;
            int row = v >> 2, kv = v & 3;
            *(uint4*)&As[row * 40 + kv * 8] =
                *(const uint4*)&tokens[(size_t)(m0 + row) * D_ + k0 + kv * 8];
            *(uint4*)&Bs[row * 40 + kv * 8] =
                *(const uint4*)&Wkvt[(size_t)(e0 + row) * D_ + k0 + kv * 8];
        }
        __syncthreads();
        V16 a[4], bb[4];
        #pragma unroll
        for (int i = 0; i < 4; ++i)
            a[i].u = *(const uint4*)&As[(wr * 64 + i * 16 + l16) * 40 + quad * 8];
        #pragma unroll
        for (int j = 0; j < 4; ++j)
            bb[j].u = *(const uint4*)&Bs[(wc * 64 + j * 16 + l16) * 40 + quad * 8];
        #pragma unroll
        for (int i = 0; i < 4; ++i)
            #pragma unroll
            for (int j = 0; j < 4; ++j)
                acc[i][j] = __builtin_amdgcn_mfma_f32_16x16x32_bf16(a[i].v, bb[j].v, acc[i][j], 0, 0, 0);
        __syncthreads();
    }

    float bcol[4];
    #pragma unroll
    for (int j = 0; j < 4; ++j)
        bcol[j] = bias_kv[e0 + wc * 64 + j * 16 + l16];

    ushort* Ct = smem;
    if (!isV) {
        // Ct[e][m], stride 136
        #pragma unroll
        for (int i = 0; i < 4; ++i)
            #pragma unroll
            for (int j = 0; j < 4; ++j) {
                int e_l = wc * 64 + j * 16 + l16;
                int m_b = wr * 64 + i * 16 + quad * 4;
                ushort4 p;
                p.x = f2b(acc[i][j][0] + bcol[j]);
                p.y = f2b(acc[i][j][1] + bcol[j]);
                p.z = f2b(acc[i][j][2] + bcol[j]);
                p.w = f2b(acc[i][j][3] + bcol[j]);
                *(ushort4*)&Ct[e_l * 136 + m_b] = p;
            }
        __syncthreads();
        int e_l = tid >> 1, half = tid & 1;
        int c = ein + e_l;
        int h = c / HD_, hd = c % HD_;
        size_t dst = ((((size_t)l * B_ + b) * H_ + h) * HD_ + hd) * N_ + ntok0 + half * 64;
        #pragma unroll
        for (int p8 = 0; p8 < 8; ++p8)
            *(uint4*)&Kt[dst + p8 * 8] = *(const uint4*)&Ct[e_l * 136 + half * 64 + p8 * 8];
    } else {
        // Ct[m][e], stride 136
        #pragma unroll
        for (int i = 0; i < 4; ++i)
            #pragma unroll
            for (int j = 0; j < 4; ++j) {
                int e_l = wc * 64 + j * 16 + l16;
                int m_b = wr * 64 + i * 16 + quad * 4;
                #pragma unroll
                for (int r = 0; r < 4; ++r)
                    Ct[(m_b + r) * 136 + e_l] = f2b(acc[i][j][r] + bcol[j]);
            }
        __syncthreads();
        int m_l = tid >> 1, half = tid & 1;
        #pragma unroll
        for (int p = 0; p < 8; ++p) {
            int e_s = half * 64 + p * 8;
            int c = ein + e_s;
            int h = c / HD_, hd = c % HD_;
            size_t dst = ((((size_t)l * B_ + b) * H_ + h) * N_ + ntok0 + m_l) * HD_ + hd;
            *(uint4*)&Vv[dst] = *(const uint4*)&Ct[m_l * 136 + e_s];
        }
    }
}

// ---------------- small MFMA GEMM: C[256 x Nc] from A[256 x K] ----------------
// AVAR: 0 = bf16 A, 1 = fp32 A normalized by stats, 2 = fp32 A plain
// OMODE: 0 = bf16 store, 1 = gelu->bf16 store, 2 = fp32 accumulate
template<int AVAR, int OMODE>
__global__ __launch_bounds__(256) void gemm_s(const void* __restrict__ Av,
                                              const float* __restrict__ stats,
                                              const ushort* __restrict__ Bt,
                                              const float* __restrict__ bias,
                                              void* __restrict__ Cv,
                                              int K, int Nc) {
    __shared__ ushort As[64 * 40];
    __shared__ ushort Bs[64 * 40];
    int tid = threadIdx.x;
    int m0 = blockIdx.y * 64, e0 = blockIdx.x * 64;
    int w = tid >> 6, lane = tid & 63, quad = lane >> 4, l16 = lane & 15;
    f32x4v acc[4];
    #pragma unroll
    for (int i = 0; i < 4; ++i) acc[i] = (f32x4v)(0.0f);
    bool doA = tid < 128;
    int t2 = tid & 127;

    for (int k0 = 0; k0 < K; k0 += 32) {
        #pragma unroll
        for (int vv = 0; vv < 2; ++vv) {
            int v = t2 + vv * 128;
            int row = v >> 2, kv = v & 3;
            if (doA) {
                if (AVAR == 0) {
                    *(uint4*)&As[row * 40 + kv * 8] =
                        *(const uint4*)((const ushort*)Av + (size_t)(m0 + row) * K + k0 + kv * 8);
                } else {
                    const float* Af = (const float*)Av + (size_t)(m0 + row) * K + k0 + kv * 8;
                    float4 f0 = *(const float4*)Af;
                    float4 f1 = *(const float4*)(Af + 4);
                    if (AVAR == 1) {
                        float mn = stats[(m0 + row) * 2], rs = stats[(m0 + row) * 2 + 1];
                        f0.x = (f0.x - mn) * rs; f0.y = (f0.y - mn) * rs;
                        f0.z = (f0.z - mn) * rs; f0.w = (f0.w - mn) * rs;
                        f1.x = (f1.x - mn) * rs; f1.y = (f1.y - mn) * rs;
                        f1.z = (f1.z - mn) * rs; f1.w = (f1.w - mn) * rs;
                    }
                    ushort4 lo, hi;
                    lo.x = f2b(f0.x); lo.y = f2b(f0.y); lo.z = f2b(f0.z); lo.w = f2b(f0.w);
                    hi.x = f2b(f1.x); hi.y = f2b(f1.y); hi.z = f2b(f1.z); hi.w = f2b(f1.w);
                    *(ushort4*)&As[row * 40 + kv * 8] = lo;
                    *(ushort4*)&As[row * 40 + kv * 8 + 4] = hi;
                }
            } else {
                *(uint4*)&Bs[row * 40 + kv * 8] =
                    *(const uint4*)&Bt[(size_t)(e0 + row) * K + k0 + kv * 8];
            }
        }
        __syncthreads();
        V16 bb;
        bb.u = *(const uint4*)&Bs[(w * 16 + l16) * 40 + quad * 8];
        #pragma unroll
        for (int i = 0; i < 4; ++i) {
            V16 a;
            a.u = *(const uint4*)&As[(i * 16 + l16) * 40 + quad * 8];
            acc[i] = __builtin_amdgcn_mfma_f32_16x16x32_bf16(a.v, bb.v, acc[i], 0, 0, 0);
        }
        __syncthreads();
    }

    int n = e0 + w * 16 + l16;
    float bn = bias[n];
    #pragma unroll
    for (int i = 0; i < 4; ++i) {
        #pragma unroll
        for (int r = 0; r < 4; ++r) {
            int m = m0 + i * 16 + quad * 4 + r;
            float v = acc[i][r] + bn;
            if (OMODE == 1) v = gelu_f(v);
            if (OMODE == 2) ((float*)Cv)[(size_t)m * Nc + n] += v;
            else            ((ushort*)Cv)[(size_t)m * Nc + n] = f2b(v);
        }
    }
}

// ---------------- row stats (mean, rstd) of fp32 x ----------------
__global__ __launch_bounds__(256) void stats_kernel(const float* __restrict__ x,
                                                    float* __restrict__ stats) {
    int b = blockIdx.x, tid = threadIdx.x;
    float s = 0, ss = 0;
    #pragma unroll
    for (int r = 0; r < 3; ++r) {
        float v = x[b * D_ + tid + r * 256];
        s += v; ss += v * v;
    }
    __shared__ float red[4];
    s = blockSum(s, red, tid);
    ss = blockSum(ss, red, tid);
    float mean = s * (1.0f / D_);
    float var = ss * (1.0f / D_) - mean * mean;
    if (tid == 0) { stats[b * 2] = mean; stats[b * 2 + 1] = rsqrtf(var + 1e-5f); }
}

// ---------------- pre-step: x += relu(LN(cp@w_pp+b_pp)) + te; emit stats ----------------
__global__ __launch_bounds__(256) void prestep_kernel(float* __restrict__ x,
                                                      float* __restrict__ stats,
                                                      const float* __restrict__ cp,
                                                      const float* __restrict__ w_pp,
                                                      const float* __restrict__ b_pp,
                                                      const float* __restrict__ g_pp,
                                                      const float* __restrict__ be_pp,
                                                      const float* __restrict__ te) {
    int b = blockIdx.x, tid = threadIdx.x;
    float c0 = cp[b * 2], c1 = cp[b * 2 + 1];
    float t[3];
    float s = 0, ss = 0;
    #pragma unroll
    for (int r = 0; r < 3; ++r) {
        int d = tid + r * 256;
        t[r] = c0 * w_pp[d] + c1 * w_pp[D_ + d] + b_pp[d];
        s += t[r]; ss += t[r] * t[r];
    }
    __shared__ float red[4];
    s = blockSum(s, red, tid);
    ss = blockSum(ss, red, tid);
    float mean = s * (1.0f / D_);
    float var = ss * (1.0f / D_) - mean * mean;
    float rinv = rsqrtf(var + 1e-5f);
    float s2 = 0, ss2 = 0;
    float nv[3];
    #pragma unroll
    for (int r = 0; r < 3; ++r) {
        int d = tid + r * 256;
        float pq = (t[r] - mean) * rinv * g_pp[d] + be_pp[d];
        pq = fmaxf(pq, 0.0f);
        nv[r] = x[b * D_ + d] + pq + te[d];
        x[b * D_ + d] = nv[r];
        s2 += nv[r]; ss2 += nv[r] * nv[r];
    }
    s2 = blockSum(s2, red, tid);
    ss2 = blockSum(ss2, red, tid);
    float mean2 = s2 * (1.0f / D_);
    float var2 = ss2 * (1.0f / D_) - mean2 * mean2;
    if (tid == 0) { stats[b * 2] = mean2; stats[b * 2 + 1] = rsqrtf(var2 + 1e-5f); }
}

// ---------------- single-query attention (bf16 q/K/V, bf16 out) ----------------
__global__ __launch_bounds__(256) void attn_kernel(const ushort* __restrict__ q,
                                                   const ushort* __restrict__ Kt,
                                                   const ushort* __restrict__ Vv,
                                                   ushort* __restrict__ att) {
    int b = blockIdx.y, h = blockIdx.x, tid = threadIdx.x;
    __shared__ float qs[96];
    __shared__ float sc[256];
    __shared__ float red[4];
    __shared__ float opart[4][96];
    if (tid < 96) qs[tid] = b2f(q[b * D_ + h * 96 + tid]);
    __syncthreads();
    const ushort* Kp = Kt + ((size_t)(b * H_ + h)) * HD_ * N_;
    float acc = 0;
    #pragma unroll 8
    for (int hd = 0; hd < 96; ++hd)
        acc += qs[hd] * b2f(Kp[hd * N_ + tid]);
    acc *= 0.10206207261596575f;
    int w = tid >> 6, lane = tid & 63;
    float m = acc;
    for (int off = 32; off; off >>= 1) m = fmaxf(m, __shfl_xor(m, off, 64));
    if (lane == 0) red[w] = m;
    __syncthreads();
    m = fmaxf(fmaxf(red[0], red[1]), fmaxf(red[2], red[3]));
    __syncthreads();
    float e = expf(acc - m);
    float ssum = e;
    for (int off = 32; off; off >>= 1) ssum += __shfl_xor(ssum, off, 64);
    if (lane == 0) red[w] = ssum;
    __syncthreads();
    float tot = red[0] + red[1] + red[2] + red[3];
    sc[tid] = e / tot;
    __syncthreads();
    const ushort* Vp = Vv + ((size_t)(b * H_ + h)) * N_ * HD_;
    float o0 = 0, o1 = 0;
    for (int i = 0; i < 64; ++i) {
        int n = w * 64 + i;
        float a = sc[n];
        const ushort* vrow = Vp + n * HD_;
        o0 += a * b2f(vrow[lane]);
        if (lane < 32) o1 += a * b2f(vrow[64 + lane]);
    }
    opart[w][lane] = o0;
    if (lane < 32) opart[w][64 + lane] = o1;
    __syncthreads();
    if (tid < 96) att[b * D_ + h * 96 + tid] =
        f2b(opart[0][tid] + opart[1][tid] + opart[2][tid] + opart[3][tid]);
}

// ---------------- final ----------------
__global__ __launch_bounds__(256) void final_kernel(const ushort* __restrict__ dech,
                                                    const float* __restrict__ w_dec2,
                                                    const float* __restrict__ b_dec2,
                                                    float* __restrict__ cp,
                                                    float* __restrict__ out,
                                                    int t) {
    int b = blockIdx.x, tid = threadIdx.x;
    float p0 = 0, p1 = 0;
    for (int k = tid; k < D_; k += 256) {
        float v = b2f(dech[b * D_ + k]);
        p0 += v * w_dec2[k * 2];
        p1 += v * w_dec2[k * 2 + 1];
    }
    __shared__ float red[4];
    p0 = blockSum(p0, red, tid);
    p1 = blockSum(p1, red, tid);
    if (tid == 0) {
        float c0 = cp[b * 2] + p0 + b_dec2[0];
        float c1 = cp[b * 2 + 1] + p1 + b_dec2[1];
        cp[b * 2] = c0;
        cp[b * 2 + 1] = c1;
        out[(b * T_ + t) * 2] = c0;
        out[(b * T_ + t) * 2 + 1] = c1;
    }
}

extern "C" void kernel_launch(void* const* d_in, const int* in_sizes, int n_in,
                              void* d_out, int out_size, void* d_ws, size_t ws_size,
                              hipStream_t stream) {
    const float* feats   = (const float*)d_in[0];
    const float* past    = (const float*)d_in[1];
    const float* w_qinit = (const float*)d_in[2];
    const float* b_qinit = (const float*)d_in[3];
    const float* pos_enc = (const float*)d_in[4];
    const float* w_pp    = (const float*)d_in[5];
    const float* b_pp    = (const float*)d_in[6];
    const float* g_pp    = (const float*)d_in[7];
    const float* be_pp   = (const float*)d_in[8];
    const float* time_emb= (const float*)d_in[9];
    const float* Wq      = (const float*)d_in[10];
    const float* bq      = (const float*)d_in[11];
    const float* Wk      = (const float*)d_in[12];
    const float* bk      = (const float*)d_in[13];
    const float* Wv      = (const float*)d_in[14];
    const float* bv      = (const float*)d_in[15];
    const float* Wo      = (const float*)d_in[16];
    const float* bo      = (const float*)d_in[17];
    const float* ln1_g   = (const float*)d_in[18];
    const float* ln1_b   = (const float*)d_in[19];
    const float* W1      = (const float*)d_in[20];
    const float* b1      = (const float*)d_in[21];
    const float* W2      = (const float*)d_in[22];
    const float* b2      = (const float*)d_in[23];
    const float* ln2_g   = (const float*)d_in[24];
    const float* ln2_b   = (const float*)d_in[25];
    const float* w_dec1  = (const float*)d_in[26];
    const float* b_dec1  = (const float*)d_in[27];
    const float* w_dec2  = (const float*)d_in[28];
    const float* b_dec2  = (const float*)d_in[29];
    const int*   intent  = (const int*)d_in[30];
    float* out = (float*)d_out;

    const size_t WD = (size_t)D_ * D_;        // 589824
    const size_t WD4 = (size_t)D_ * D4_;      // 2359296
    const size_t kv_elems = (size_t)L_ * B_ * H_ * HD_ * N_;   // 100,663,296
    const size_t kv_l = (size_t)B_ * H_ * HD_ * N_;

    char* wp = (char*)d_ws;
    ushort* Kt     = (ushort*)wp; wp += kv_elems * 2;
    ushort* Vv     = (ushort*)wp; wp += kv_elems * 2;
    ushort* tokens = (ushort*)wp; wp += (size_t)B_ * N_ * D_ * 2;
    ushort* Wkvt   = (ushort*)wp; wp += 4 * WD * 2;
    ushort* Wqt    = (ushort*)wp; wp += 2 * WD * 2;
    ushort* Wot    = (ushort*)wp; wp += 2 * WD * 2;
    ushort* W1t    = (ushort*)wp; wp += 2 * WD4 * 2;
    ushort* W2t    = (ushort*)wp; wp += 2 * WD4 * 2;
    ushort* dec1t  = (ushort*)wp; wp += WD * 2;
    float* bias_kv = (float*)wp;  wp += 4 * D_ * 4;
    float* bqe     = (float*)wp;  wp += 2 * D_ * 4;
    float* b1e     = (float*)wp;  wp += 2 * D4_ * 4;
    float* x       = (float*)wp;  wp += (size_t)B_ * D_ * 4;
    float* stats   = (float*)wp;  wp += (size_t)B_ * 2 * 4;
    ushort* qbuf   = (ushort*)wp; wp += (size_t)B_ * D_ * 2;
    ushort* attbuf = (ushort*)wp; wp += (size_t)B_ * D_ * 2;
    ushort* h1     = (ushort*)wp; wp += (size_t)B_ * D4_ * 2;
    ushort* dech   = (ushort*)wp; wp += (size_t)B_ * D_ * 2;
    float* cp      = (float*)wp;  wp += (size_t)B_ * 2 * 4;

    // ---- prep ----
    initcp_kernel<<<2, 256, 0, stream>>>(past, cp);
    context_kernel<<<B_, 256, 0, stream>>>(past, w_qinit, b_qinit, intent, x);
    token_prep<<<dim3(12, 4, 256), 256, 0, stream>>>(feats, pos_enc, tokens);
    kvbias_prep<<<12, 256, 0, stream>>>(bk, bv, bias_kv);
    for (int l = 0; l < L_; ++l) {
        transpose_w<<<dim3(24, 24), 256, 0, stream>>>(Wk + l * WD, Wkvt + (2 * l + 0) * WD, nullptr, D_, D_);
        transpose_w<<<dim3(24, 24), 256, 0, stream>>>(Wv + l * WD, Wkvt + (2 * l + 1) * WD, nullptr, D_, D_);
        transpose_w<<<dim3(24, 24), 256, 0, stream>>>(Wq + l * WD, Wqt + l * WD, ln1_g + l * D_, D_, D_);
        transpose_w<<<dim3(24, 24), 256, 0, stream>>>(Wo + l * WD, Wot + l * WD, nullptr, D_, D_);
        transpose_w<<<dim3(96, 24), 256, 0, stream>>>(W1 + l * WD4, W1t + l * WD4, ln2_g + l * D_, D_, D4_);
        transpose_w<<<dim3(24, 96), 256, 0, stream>>>(W2 + l * WD4, W2t + l * WD4, nullptr, D4_, D_);
        bias_eff_kernel<<<3, 256, 0, stream>>>(Wq + l * WD, bq + l * D_, ln1_b + l * D_, bqe + l * D_, D_);
        bias_eff_kernel<<<12, 256, 0, stream>>>(W1 + l * WD4, b1 + l * D4_, ln2_b + l * D_, b1e + l * D4_, D4_);
    }
    transpose_w<<<dim3(24, 24), 256, 0, stream>>>(w_dec1, dec1t, nullptr, D_, D_);

    kv_gemm_mfma<<<dim3(24, 512), 256, 0, stream>>>(tokens, Wkvt, bias_kv, Kt, Vv);

    // ---- sequential steps ----
    for (int t = 0; t < T_; ++t) {
        prestep_kernel<<<B_, 256, 0, stream>>>(x, stats, cp, w_pp, b_pp, g_pp, be_pp,
                                               time_emb + (size_t)t * D_);
        for (int l = 0; l < L_; ++l) {
            gemm_s<1, 0><<<dim3(12, 4), 256, 0, stream>>>(x, stats, Wqt + l * WD,
                                                          bqe + l * D_, qbuf, D_, D_);
            attn_kernel<<<dim3(H_, B_), 256, 0, stream>>>(qbuf, Kt + l * kv_l, Vv + l * kv_l, attbuf);
            gemm_s<0, 2><<<dim3(12, 4), 256, 0, stream>>>(attbuf, nullptr, Wot + l * WD,
                                                          bo + l * D_, x, D_, D_);
            stats_kernel<<<B_, 256, 0, stream>>>(x, stats);
            gemm_s<1, 1><<<dim3(48, 4), 256, 0, stream>>>(x, stats, W1t + l * WD4,
                                                          b1e + l * D4_, h1, D_, D4_);
            gemm_s<0, 2><<<dim3(12, 4), 256, 0, stream>>>(h1, nullptr, W2t + l * WD4,
                                                          b2 + l * D_, x, D4_, D_);
            if (l == 0) stats_kernel<<<B_, 256, 0, stream>>>(x, stats);
        }
        gemm_s<2, 1><<<dim3(12, 4), 256, 0, stream>>>(x, nullptr, dec1t, b_dec1, dech, D_, D_);
        final_kernel<<<B_, 256, 0, stream>>>(dech, w_dec2, b_dec2, cp, out, t);
    }
}

// Round 3
// 8822.850 us; speedup vs baseline: 2.8626x; 1.2587x over previous
//
#include <hip/hip_runtime.h>
#include <hip/hip_bf16.h>
#include <math.h>

#define B_ 256
#define D_ 768
#define N_ 256
#define L_ 2
#define H_ 8
#define T_ 20
#define HD_ 96
#define D4_ 3072

typedef float f32x4v __attribute__((ext_vector_type(4)));
typedef __bf16 bf16x8v __attribute__((ext_vector_type(8)));

union V16 { uint4 u; bf16x8v v; };

__device__ __forceinline__ ushort f2b(float f) {
    union { float f; unsigned u; } x{f};
    unsigned r = x.u + 0x7fffu + ((x.u >> 16) & 1u);
    return (ushort)(r >> 16);
}
__device__ __forceinline__ float b2f(ushort s) {
    union { unsigned u; float f; } x{(unsigned)s << 16};
    return x.f;
}
__device__ __forceinline__ float gelu_f(float v) {
    return 0.5f * v * (1.0f + erff(v * 0.7071067811865476f));
}
__device__ __forceinline__ float blockSum(float v, float* red, int tid) {
    for (int off = 32; off; off >>= 1) v += __shfl_down(v, off, 64);
    int w = tid >> 6, lane = tid & 63;
    if (lane == 0) red[w] = v;
    __syncthreads();
    float r = red[0] + red[1] + red[2] + red[3];
    __syncthreads();
    return r;
}

// ---------------- context + cp init + prestep(t=0), all per-row ----------------
__global__ __launch_bounds__(256) void context_kernel(const float* __restrict__ past,
                                                      const float* __restrict__ w_qinit,
                                                      const float* __restrict__ b_qinit,
                                                      const int* __restrict__ intent,
                                                      const float* __restrict__ w_pp,
                                                      const float* __restrict__ b_pp,
                                                      const float* __restrict__ g_pp,
                                                      const float* __restrict__ be_pp,
                                                      const float* __restrict__ te0,
                                                      float* __restrict__ x,
                                                      float* __restrict__ cp) {
    int b = blockIdx.x, tid = threadIdx.x;
    __shared__ float ps[96];
    __shared__ int oidx;
    __shared__ float red[4];
    if (tid < 96) ps[tid] = past[b * 96 + tid];
    if (tid == 0) {
        int iv = intent[b] - 1;
        oidx = iv < 0 ? 0 : (iv > 2 ? 2 : iv);
    }
    __syncthreads();
    float ctx[3];
    #pragma unroll
    for (int r = 0; r < 3; ++r) {
        int d = tid + r * 256;
        float acc = w_qinit[oidx * D_ + d] + b_qinit[d];
        #pragma unroll 8
        for (int p = 0; p < 96; ++p) acc += ps[p] * w_qinit[(3 + p) * D_ + d];
        ctx[r] = acc;
    }
    float c0 = ps[90], c1 = ps[91];   // past[:, -1, 0:2]
    if (tid == 0) { cp[b * 2] = c0; cp[b * 2 + 1] = c1; }
    // prestep for t=0
    float t[3];
    float s = 0, ss = 0;
    #pragma unroll
    for (int r = 0; r < 3; ++r) {
        int d = tid + r * 256;
        t[r] = c0 * w_pp[d] + c1 * w_pp[D_ + d] + b_pp[d];
        s += t[r]; ss += t[r] * t[r];
    }
    s = blockSum(s, red, tid);
    ss = blockSum(ss, red, tid);
    float mean = s * (1.0f / D_);
    float var = ss * (1.0f / D_) - mean * mean;
    float rinv = rsqrtf(var + 1e-5f);
    #pragma unroll
    for (int r = 0; r < 3; ++r) {
        int d = tid + r * 256;
        float pq = fmaxf((t[r] - mean) * rinv * g_pp[d] + be_pp[d], 0.0f);
        x[b * D_ + d] = ctx[r] + pq + te0[d];
    }
}

// ---------------- tokens bf16 k-major ----------------
__global__ __launch_bounds__(256) void token_prep(const float* __restrict__ feats,
                                                  const float* __restrict__ pos_enc,
                                                  ushort* __restrict__ tokens) {
    int b = blockIdx.z;
    int d0 = blockIdx.x * 64, n0 = blockIdx.y * 64;
    __shared__ float tile[64][65];
    int tid = threadIdx.x;
    int nl = tid & 63, dl0 = tid >> 6;
    const float* fb = feats + ((size_t)b * D_ + d0) * N_ + n0;
    #pragma unroll
    for (int i = 0; i < 16; ++i) {
        int dl = dl0 + i * 4;
        tile[dl][nl] = fb[(size_t)dl * N_ + nl];
    }
    __syncthreads();
    int dq = (tid & 15) * 4;
    int ng = tid >> 4;
    #pragma unroll
    for (int i = 0; i < 4; ++i) {
        int nl2 = ng + i * 16;
        int n = n0 + nl2;
        float4 p = *(const float4*)(pos_enc + (size_t)n * D_ + d0 + dq);
        ushort4 o;
        o.x = f2b(tile[dq + 0][nl2] + p.x);
        o.y = f2b(tile[dq + 1][nl2] + p.y);
        o.z = f2b(tile[dq + 2][nl2] + p.z);
        o.w = f2b(tile[dq + 3][nl2] + p.w);
        *(ushort4*)&tokens[((size_t)b * N_ + n) * D_ + d0 + dq] = o;
    }
}

// ---------------- weight transpose (+ optional row scale) fp32[K][N] -> bf16[N][K] ----------------
__global__ __launch_bounds__(256) void transpose_w(const float* __restrict__ W,
                                                   ushort* __restrict__ out,
                                                   const float* __restrict__ scale,
                                                   int K, int N) {
    __shared__ float t[32][33];
    int k0 = blockIdx.y * 32, n0 = blockIdx.x * 32;
    int tx = threadIdx.x & 31, ty = threadIdx.x >> 5;
    #pragma unroll
    for (int i = 0; i < 4; ++i)
        t[ty + i * 8][tx] = W[(size_t)(k0 + ty + i * 8) * N + n0 + tx];
    __syncthreads();
    #pragma unroll
    for (int i = 0; i < 4; ++i) {
        int n = n0 + ty + i * 8, k = k0 + tx;
        float v = t[tx][ty + i * 8];
        if (scale) v *= scale[k];
        out[(size_t)n * K + k] = f2b(v);
    }
}

// ---------------- plain cast fp32 -> bf16 (same layout) ----------------
__global__ void cast_w(const float* __restrict__ W, ushort* __restrict__ out, int n) {
    int i = blockIdx.x * 256 + threadIdx.x;
    if (i < n) out[i] = f2b(W[i]);
}

// ---------------- bias_eff = bias + b_ln @ W ----------------
__global__ __launch_bounds__(256) void bias_eff_kernel(const float* __restrict__ W,
                                                       const float* __restrict__ bias,
                                                       const float* __restrict__ lb,
                                                       float* __restrict__ be, int Nc) {
    int n = blockIdx.x * 256 + threadIdx.x;
    float a = bias[n];
    for (int k = 0; k < D_; ++k) a += lb[k] * W[(size_t)k * Nc + n];
    be[n] = a;
}

__global__ void kvbias_prep(const float* __restrict__ bk, const float* __restrict__ bv,
                            float* __restrict__ bc) {
    int i = blockIdx.x * 256 + threadIdx.x;
    int mi = i / D_, c = i % D_;
    int l = mi >> 1;
    bc[i] = (mi & 1 ? bv : bk)[l * D_ + c];
}

// ---------------- K/V projection MFMA GEMM ----------------
__global__ __launch_bounds__(256) void kv_gemm_mfma(const ushort* __restrict__ tokens,
                                                    const ushort* __restrict__ Wkvt,
                                                    const float* __restrict__ bias_kv,
                                                    ushort* __restrict__ Kt,
                                                    ushort* __restrict__ Vv) {
    int e0 = blockIdx.x * 128;
    int mi = e0 / D_;
    int ein = e0 % D_;
    int l = mi >> 1, isV = mi & 1;
    int m0 = blockIdx.y * 128;
    int b = m0 >> 8, ntok0 = m0 & 255;
    __shared__ ushort smem[17408];
    ushort* As = smem;
    ushort* Bs = smem + 128 * 40;
    int tid = threadIdx.x;
    int w = tid >> 6, lane = tid & 63, quad = lane >> 4, l16 = lane & 15;
    int wr = w >> 1, wc = w & 1;
    f32x4v acc[4][4];
    #pragma unroll
    for (int i = 0; i < 4; ++i)
        #pragma unroll
        for (int j = 0; j < 4; ++j) acc[i][j] = (f32x4v)(0.0f);

    for (int k0 = 0; k0 < D_; k0 += 32) {
        #pragma unroll
        for (int vv = 0; vv < 2; ++vv) {
            int v = tid + vv * 256;
            int row = v >> 2, kv = v & 3;
            *(uint4*)&As[row * 40 + kv * 8] =
                *(const uint4*)&tokens[(size_t)(m0 + row) * D_ + k0 + kv * 8];
            *(uint4*)&Bs[row * 40 + kv * 8] =
                *(const uint4*)&Wkvt[(size_t)(e0 + row) * D_ + k0 + kv * 8];
        }
        __syncthreads();
        V16 a[4], bb[4];
        #pragma unroll
        for (int i = 0; i < 4; ++i)
            a[i].u = *(const uint4*)&As[(wr * 64 + i * 16 + l16) * 40 + quad * 8];
        #pragma unroll
        for (int j = 0; j < 4; ++j)
            bb[j].u = *(const uint4*)&Bs[(wc * 64 + j * 16 + l16) * 40 + quad * 8];
        #pragma unroll
        for (int i = 0; i < 4; ++i)
            #pragma unroll
            for (int j = 0; j < 4; ++j)
                acc[i][j] = __builtin_amdgcn_mfma_f32_16x16x32_bf16(a[i].v, bb[j].v, acc[i][j], 0, 0, 0);
        __syncthreads();
    }

    float bcol[4];
    #pragma unroll
    for (int j = 0; j < 4; ++j)
        bcol[j] = bias_kv[e0 + wc * 64 + j * 16 + l16];

    ushort* Ct = smem;
    if (!isV) {
        #pragma unroll
        for (int i = 0; i < 4; ++i)
            #pragma unroll
            for (int j = 0; j < 4; ++j) {
                int e_l = wc * 64 + j * 16 + l16;
                int m_b = wr * 64 + i * 16 + quad * 4;
                ushort4 p;
                p.x = f2b(acc[i][j][0] + bcol[j]);
                p.y = f2b(acc[i][j][1] + bcol[j]);
                p.z = f2b(acc[i][j][2] + bcol[j]);
                p.w = f2b(acc[i][j][3] + bcol[j]);
                *(ushort4*)&Ct[e_l * 136 + m_b] = p;
            }
        __syncthreads();
        int e_l = tid >> 1, half = tid & 1;
        int c = ein + e_l;
        int h = c / HD_, hd = c % HD_;
        size_t dst = ((((size_t)l * B_ + b) * H_ + h) * HD_ + hd) * N_ + ntok0 + half * 64;
        #pragma unroll
        for (int p8 = 0; p8 < 8; ++p8)
            *(uint4*)&Kt[dst + p8 * 8] = *(const uint4*)&Ct[e_l * 136 + half * 64 + p8 * 8];
    } else {
        #pragma unroll
        for (int i = 0; i < 4; ++i)
            #pragma unroll
            for (int j = 0; j < 4; ++j) {
                int e_l = wc * 64 + j * 16 + l16;
                int m_b = wr * 64 + i * 16 + quad * 4;
                #pragma unroll
                for (int r = 0; r < 4; ++r)
                    Ct[(m_b + r) * 136 + e_l] = f2b(acc[i][j][r] + bcol[j]);
            }
        __syncthreads();
        int m_l = tid >> 1, half = tid & 1;
        #pragma unroll
        for (int p = 0; p < 8; ++p) {
            int e_s = half * 64 + p * 8;
            int c = ein + e_s;
            int h = c / HD_, hd = c % HD_;
            size_t dst = ((((size_t)l * B_ + b) * H_ + h) * N_ + ntok0 + m_l) * HD_ + hd;
            *(uint4*)&Vv[dst] = *(const uint4*)&Ct[m_l * 136 + e_s];
        }
    }
}

// ---------------- small MFMA GEMM, software-pipelined ----------------
// AVAR: 0 = bf16 A, 1 = fp32 A normalized by inline row stats (requires STATS=1)
// OMODE: 0 = bf16 store, 1 = gelu->bf16 store, 2 = fp32 atomicAdd (bias on z==0)
template<int AVAR, int OMODE, int STATS, int KSPLIT>
__global__ __launch_bounds__(256) void gemm_s(const void* __restrict__ Av,
                                              const ushort* __restrict__ Bt,
                                              const float* __restrict__ bias,
                                              void* __restrict__ Cv,
                                              int K, int Nc) {
    __shared__ ushort As[64 * 40];
    __shared__ ushort Bs[64 * 40];
    __shared__ float smst[64][2];
    int tid = threadIdx.x;
    int m0 = blockIdx.y * 64, e0 = blockIdx.x * 64;
    int kslice = K / KSPLIT;
    int kbeg = blockIdx.z * kslice, kend = kbeg + kslice;
    int w = tid >> 6, lane = tid & 63, quad = lane >> 4, l16 = lane & 15;

    if (STATS) {
        // inline LN stats for rows m0..m0+63 (4 threads/row, K==768)
        int row = tid >> 2, part = tid & 3;
        const float* xr = (const float*)Av + (size_t)(m0 + row) * K + part * 192;
        float s = 0, ss = 0;
        #pragma unroll 4
        for (int i = 0; i < 192; i += 4) {
            float4 f = *(const float4*)(xr + i);
            s += f.x + f.y + f.z + f.w;
            ss += f.x * f.x + f.y * f.y + f.z * f.z + f.w * f.w;
        }
        s += __shfl_xor(s, 1, 64);  s += __shfl_xor(s, 2, 64);
        ss += __shfl_xor(ss, 1, 64); ss += __shfl_xor(ss, 2, 64);
        if (part == 0) {
            float mean = s * (1.0f / 768.0f);
            float var = ss * (1.0f / 768.0f) - mean * mean;
            smst[row][0] = mean;
            smst[row][1] = rsqrtf(var + 1e-5f);
        }
        __syncthreads();
    }

    bool doA = tid < 128;
    int t2 = tid & 127;
    f32x4v acc[4];
    #pragma unroll
    for (int i = 0; i < 4; ++i) acc[i] = (f32x4v)(0.0f);

    auto fetch = [&](int kk, int vv) -> uint4 {
        int v = t2 + vv * 128;
        int row = v >> 2, kq = v & 3;
        if (doA) {
            if (AVAR == 0) {
                return *(const uint4*)((const ushort*)Av + (size_t)(m0 + row) * K + kk + kq * 8);
            } else {
                const float* Af = (const float*)Av + (size_t)(m0 + row) * K + kk + kq * 8;
                float4 f0 = *(const float4*)Af;
                float4 f1 = *(const float4*)(Af + 4);
                float mn = smst[row][0], rs = smst[row][1];
                f0.x = (f0.x - mn) * rs; f0.y = (f0.y - mn) * rs;
                f0.z = (f0.z - mn) * rs; f0.w = (f0.w - mn) * rs;
                f1.x = (f1.x - mn) * rs; f1.y = (f1.y - mn) * rs;
                f1.z = (f1.z - mn) * rs; f1.w = (f1.w - mn) * rs;
                uint4 u;
                u.x = (unsigned)f2b(f0.x) | ((unsigned)f2b(f0.y) << 16);
                u.y = (unsigned)f2b(f0.z) | ((unsigned)f2b(f0.w) << 16);
                u.z = (unsigned)f2b(f1.x) | ((unsigned)f2b(f1.y) << 16);
                u.w = (unsigned)f2b(f1.z) | ((unsigned)f2b(f1.w) << 16);
                return u;
            }
        } else {
            return *(const uint4*)&Bt[(size_t)(e0 + row) * K + kk + kq * 8];
        }
    };
    auto stash = [&](int vv, uint4 u) {
        int v = t2 + vv * 128;
        int row = v >> 2, kq = v & 3;
        ushort* dst = doA ? As : Bs;
        *(uint4*)&dst[row * 40 + kq * 8] = u;
    };
    auto compute = [&]() {
        V16 bb;
        bb.u = *(const uint4*)&Bs[(w * 16 + l16) * 40 + quad * 8];
        #pragma unroll
        for (int i = 0; i < 4; ++i) {
            V16 a;
            a.u = *(const uint4*)&As[(i * 16 + l16) * 40 + quad * 8];
            acc[i] = __builtin_amdgcn_mfma_f32_16x16x32_bf16(a.v, bb.v, acc[i], 0, 0, 0);
        }
    };

    // prologue
    {
        uint4 p0 = fetch(kbeg, 0), p1 = fetch(kbeg, 1);
        stash(0, p0); stash(1, p1);
    }
    __syncthreads();
    for (int kk = kbeg + 32; kk < kend; kk += 32) {
        uint4 p0 = fetch(kk, 0), p1 = fetch(kk, 1);
        compute();
        __syncthreads();
        stash(0, p0); stash(1, p1);
        __syncthreads();
    }
    compute();

    int n = e0 + w * 16 + l16;
    float bn = 0.0f;
    if (OMODE != 2 || blockIdx.z == 0) bn = bias[n];
    #pragma unroll
    for (int i = 0; i < 4; ++i) {
        #pragma unroll
        for (int r = 0; r < 4; ++r) {
            int m = m0 + i * 16 + quad * 4 + r;
            float v = acc[i][r] + bn;
            if (OMODE == 1) v = gelu_f(v);
            if (OMODE == 2) atomicAdd((float*)Cv + (size_t)m * Nc + n, v);
            else            ((ushort*)Cv)[(size_t)m * Nc + n] = f2b(v);
        }
    }
}

// ---------------- single-query attention (bf16 q/K/V, bf16 out) ----------------
__global__ __launch_bounds__(256) void attn_kernel(const ushort* __restrict__ q,
                                                   const ushort* __restrict__ Kt,
                                                   const ushort* __restrict__ Vv,
                                                   ushort* __restrict__ att) {
    int b = blockIdx.y, h = blockIdx.x, tid = threadIdx.x;
    __shared__ float qs[96];
    __shared__ float sc[256];
    __shared__ float red[4];
    __shared__ float opart[4][96];
    if (tid < 96) qs[tid] = b2f(q[b * D_ + h * 96 + tid]);
    __syncthreads();
    const ushort* Kp = Kt + ((size_t)(b * H_ + h)) * HD_ * N_;
    float acc = 0;
    #pragma unroll 8
    for (int hd = 0; hd < 96; ++hd)
        acc += qs[hd] * b2f(Kp[hd * N_ + tid]);
    acc *= 0.10206207261596575f;
    int w = tid >> 6, lane = tid & 63;
    float m = acc;
    for (int off = 32; off; off >>= 1) m = fmaxf(m, __shfl_xor(m, off, 64));
    if (lane == 0) red[w] = m;
    __syncthreads();
    m = fmaxf(fmaxf(red[0], red[1]), fmaxf(red[2], red[3]));
    __syncthreads();
    float e = expf(acc - m);
    float ssum = e;
    for (int off = 32; off; off >>= 1) ssum += __shfl_xor(ssum, off, 64);
    if (lane == 0) red[w] = ssum;
    __syncthreads();
    float tot = red[0] + red[1] + red[2] + red[3];
    sc[tid] = e / tot;
    __syncthreads();
    const ushort* Vp = Vv + ((size_t)(b * H_ + h)) * N_ * HD_;
    float o0 = 0, o1 = 0;
    for (int i = 0; i < 64; ++i) {
        int n = w * 64 + i;
        float a = sc[n];
        const ushort* vrow = Vp + n * HD_;
        o0 += a * b2f(vrow[lane]);
        if (lane < 32) o1 += a * b2f(vrow[64 + lane]);
    }
    opart[w][lane] = o0;
    if (lane < 32) opart[w][64 + lane] = o1;
    __syncthreads();
    if (tid < 96) att[b * D_ + h * 96 + tid] =
        f2b(opart[0][tid] + opart[1][tid] + opart[2][tid] + opart[3][tid]);
}

// ---------------- tail: dec1 matvec + gelu + dec2 + cp update + out + prestep(t+1) ----------------
__global__ __launch_bounds__(256) void tail_kernel(float* __restrict__ x,
                                                   const ushort* __restrict__ dec1r,
                                                   const float* __restrict__ b_dec1,
                                                   const float* __restrict__ w_dec2,
                                                   const float* __restrict__ b_dec2,
                                                   float* __restrict__ cp,
                                                   float* __restrict__ out,
                                                   const float* __restrict__ time_emb,
                                                   const float* __restrict__ w_pp,
                                                   const float* __restrict__ b_pp,
                                                   const float* __restrict__ g_pp,
                                                   const float* __restrict__ be_pp,
                                                   int t) {
    int b = blockIdx.x, tid = threadIdx.x;
    __shared__ float xs[768];
    __shared__ float red[4];
    #pragma unroll
    for (int r = 0; r < 3; ++r) xs[tid + r * 256] = x[b * D_ + tid + r * 256];
    __syncthreads();
    float d0 = 0, d1 = 0, d2 = 0;
    #pragma unroll 4
    for (int k = 0; k < 768; ++k) {
        float a = xs[k];
        const ushort* wr = dec1r + (size_t)k * 768;
        d0 += a * b2f(wr[tid]);
        d1 += a * b2f(wr[tid + 256]);
        d2 += a * b2f(wr[tid + 512]);
    }
    float v0 = gelu_f(d0 + b_dec1[tid]);
    float v1 = gelu_f(d1 + b_dec1[tid + 256]);
    float v2 = gelu_f(d2 + b_dec1[tid + 512]);
    float p0 = v0 * w_dec2[tid * 2]     + v1 * w_dec2[(tid + 256) * 2]     + v2 * w_dec2[(tid + 512) * 2];
    float p1 = v0 * w_dec2[tid * 2 + 1] + v1 * w_dec2[(tid + 256) * 2 + 1] + v2 * w_dec2[(tid + 512) * 2 + 1];
    p0 = blockSum(p0, red, tid);
    p1 = blockSum(p1, red, tid);
    float c0 = cp[b * 2] + p0 + b_dec2[0];
    float c1 = cp[b * 2 + 1] + p1 + b_dec2[1];
    if (tid == 0) {
        cp[b * 2] = c0;
        cp[b * 2 + 1] = c1;
        out[(b * T_ + t) * 2] = c0;
        out[(b * T_ + t) * 2 + 1] = c1;
    }
    if (t < T_ - 1) {
        const float* te = time_emb + (size_t)(t + 1) * D_;
        float tv[3];
        float s = 0, ss = 0;
        #pragma unroll
        for (int r = 0; r < 3; ++r) {
            int d = tid + r * 256;
            tv[r] = c0 * w_pp[d] + c1 * w_pp[D_ + d] + b_pp[d];
            s += tv[r]; ss += tv[r] * tv[r];
        }
        s = blockSum(s, red, tid);
        ss = blockSum(ss, red, tid);
        float mean = s * (1.0f / D_);
        float var = ss * (1.0f / D_) - mean * mean;
        float rinv = rsqrtf(var + 1e-5f);
        #pragma unroll
        for (int r = 0; r < 3; ++r) {
            int d = tid + r * 256;
            float pq = fmaxf((tv[r] - mean) * rinv * g_pp[d] + be_pp[d], 0.0f);
            x[b * D_ + d] += pq + te[d];
        }
    }
}

extern "C" void kernel_launch(void* const* d_in, const int* in_sizes, int n_in,
                              void* d_out, int out_size, void* d_ws, size_t ws_size,
                              hipStream_t stream) {
    const float* feats   = (const float*)d_in[0];
    const float* past    = (const float*)d_in[1];
    const float* w_qinit = (const float*)d_in[2];
    const float* b_qinit = (const float*)d_in[3];
    const float* pos_enc = (const float*)d_in[4];
    const float* w_pp    = (const float*)d_in[5];
    const float* b_pp    = (const float*)d_in[6];
    const float* g_pp    = (const float*)d_in[7];
    const float* be_pp   = (const float*)d_in[8];
    const float* time_emb= (const float*)d_in[9];
    const float* Wq      = (const float*)d_in[10];
    const float* bq      = (const float*)d_in[11];
    const float* Wk      = (const float*)d_in[12];
    const float* bk      = (const float*)d_in[13];
    const float* Wv      = (const float*)d_in[14];
    const float* bv      = (const float*)d_in[15];
    const float* Wo      = (const float*)d_in[16];
    const float* bo      = (const float*)d_in[17];
    const float* ln1_g   = (const float*)d_in[18];
    const float* ln1_b   = (const float*)d_in[19];
    const float* W1      = (const float*)d_in[20];
    const float* b1      = (const float*)d_in[21];
    const float* W2      = (const float*)d_in[22];
    const float* b2      = (const float*)d_in[23];
    const float* ln2_g   = (const float*)d_in[24];
    const float* ln2_b   = (const float*)d_in[25];
    const float* w_dec1  = (const float*)d_in[26];
    const float* b_dec1  = (const float*)d_in[27];
    const float* w_dec2  = (const float*)d_in[28];
    const float* b_dec2  = (const float*)d_in[29];
    const int*   intent  = (const int*)d_in[30];
    float* out = (float*)d_out;

    const size_t WD = (size_t)D_ * D_;
    const size_t WD4 = (size_t)D_ * D4_;
    const size_t kv_elems = (size_t)L_ * B_ * H_ * HD_ * N_;
    const size_t kv_l = (size_t)B_ * H_ * HD_ * N_;

    char* wp = (char*)d_ws;
    ushort* Kt     = (ushort*)wp; wp += kv_elems * 2;
    ushort* Vv     = (ushort*)wp; wp += kv_elems * 2;
    ushort* tokens = (ushort*)wp; wp += (size_t)B_ * N_ * D_ * 2;
    ushort* Wkvt   = (ushort*)wp; wp += 4 * WD * 2;
    ushort* Wqt    = (ushort*)wp; wp += 2 * WD * 2;
    ushort* Wot    = (ushort*)wp; wp += 2 * WD * 2;
    ushort* W1t    = (ushort*)wp; wp += 2 * WD4 * 2;
    ushort* W2t    = (ushort*)wp; wp += 2 * WD4 * 2;
    ushort* dec1r  = (ushort*)wp; wp += WD * 2;
    float* bias_kv = (float*)wp;  wp += 4 * D_ * 4;
    float* bqe     = (float*)wp;  wp += 2 * D_ * 4;
    float* b1e     = (float*)wp;  wp += 2 * D4_ * 4;
    float* x       = (float*)wp;  wp += (size_t)B_ * D_ * 4;
    ushort* qbuf   = (ushort*)wp; wp += (size_t)B_ * D_ * 2;
    ushort* attbuf = (ushort*)wp; wp += (size_t)B_ * D_ * 2;
    ushort* h1     = (ushort*)wp; wp += (size_t)B_ * D4_ * 2;
    float* cp      = (float*)wp;  wp += (size_t)B_ * 2 * 4;

    // ---- prep ----
    context_kernel<<<B_, 256, 0, stream>>>(past, w_qinit, b_qinit, intent,
                                           w_pp, b_pp, g_pp, be_pp, time_emb, x, cp);
    token_prep<<<dim3(12, 4, 256), 256, 0, stream>>>(feats, pos_enc, tokens);
    kvbias_prep<<<12, 256, 0, stream>>>(bk, bv, bias_kv);
    for (int l = 0; l < L_; ++l) {
        transpose_w<<<dim3(24, 24), 256, 0, stream>>>(Wk + l * WD, Wkvt + (2 * l + 0) * WD, nullptr, D_, D_);
        transpose_w<<<dim3(24, 24), 256, 0, stream>>>(Wv + l * WD, Wkvt + (2 * l + 1) * WD, nullptr, D_, D_);
        transpose_w<<<dim3(24, 24), 256, 0, stream>>>(Wq + l * WD, Wqt + l * WD, ln1_g + l * D_, D_, D_);
        transpose_w<<<dim3(24, 24), 256, 0, stream>>>(Wo + l * WD, Wot + l * WD, nullptr, D_, D_);
        transpose_w<<<dim3(96, 24), 256, 0, stream>>>(W1 + l * WD4, W1t + l * WD4, ln2_g + l * D_, D_, D4_);
        transpose_w<<<dim3(24, 96), 256, 0, stream>>>(W2 + l * WD4, W2t + l * WD4, nullptr, D4_, D_);
        bias_eff_kernel<<<3, 256, 0, stream>>>(Wq + l * WD, bq + l * D_, ln1_b + l * D_, bqe + l * D_, D_);
        bias_eff_kernel<<<12, 256, 0, stream>>>(W1 + l * WD4, b1 + l * D4_, ln2_b + l * D_, b1e + l * D4_, D4_);
    }
    cast_w<<<(int)((WD + 255) / 256), 256, 0, stream>>>(w_dec1, dec1r, (int)WD);

    kv_gemm_mfma<<<dim3(24, 512), 256, 0, stream>>>(tokens, Wkvt, bias_kv, Kt, Vv);

    // ---- sequential steps: 11 kernels/step ----
    for (int t = 0; t < T_; ++t) {
        for (int l = 0; l < L_; ++l) {
            gemm_s<1, 0, 1, 1><<<dim3(12, 4), 256, 0, stream>>>(x, Wqt + l * WD,
                                                                bqe + l * D_, qbuf, D_, D_);
            attn_kernel<<<dim3(H_, B_), 256, 0, stream>>>(qbuf, Kt + l * kv_l, Vv + l * kv_l, attbuf);
            gemm_s<0, 2, 0, 2><<<dim3(12, 4, 2), 256, 0, stream>>>(attbuf, Wot + l * WD,
                                                                   bo + l * D_, x, D_, D_);
            gemm_s<1, 1, 1, 1><<<dim3(48, 4), 256, 0, stream>>>(x, W1t + l * WD4,
                                                                b1e + l * D4_, h1, D_, D4_);
            gemm_s<0, 2, 0, 4><<<dim3(12, 4, 4), 256, 0, stream>>>(h1, W2t + l * WD4,
                                                                   b2 + l * D_, x, D4_, D_);
        }
        tail_kernel<<<B_, 256, 0, stream>>>(x, dec1r, b_dec1, w_dec2, b_dec2, cp, out,
                                            time_emb, w_pp, b_pp, g_pp, be_pp, t);
    }
}